// Round 1
// baseline (3399.670 us; speedup 1.0000x reference)
//
#include <hip/hip_runtime.h>
#include <math.h>

#define BATCH 4096
#define NPART 100
#define PSZ   64

// ------------------------------------------------------------------
// Kernel 1: particle encoder: relu(relu(x@W1+b1)@W2+b2).mean(particles)
// One block per batch element. 256 threads.
// LDS: xs 25600B + h1 20480B + w2t 16384B = 62464B (<64KB static limit)
// ------------------------------------------------------------------
__global__ __launch_bounds__(256) void k_encoder(
    const float* __restrict__ x,
    const float* __restrict__ w1, const float* __restrict__ b1,
    const float* __restrict__ w2, const float* __restrict__ b2,
    float* __restrict__ xp)
{
    __shared__ float xs[NPART * PSZ];     // 100 x 64
    __shared__ float h1[20][256];         // one particle chunk of fc1 output
    __shared__ float w2t[16][256];        // W2 k-tile (reused as reduction buf)
    const int tid = threadIdx.x;
    const int b   = blockIdx.x;

    // stage x_b into LDS (coalesced float4)
    {
        const float4* src = (const float4*)(x + (size_t)b * (NPART * PSZ));
        float4* dst = (float4*)xs;
        for (int i = tid; i < NPART * PSZ / 4; i += 256) dst[i] = src[i];
    }
    // cache W1 column `tid` in registers (reused for all 100 particles)
    float w1c[64];
    #pragma unroll
    for (int k = 0; k < 64; ++k) w1c[k] = w1[k * 256 + tid];
    const float b1j = b1[tid];

    const int tx = tid & 63;   // 64 col-groups of 4 cols
    const int ty = tid >> 6;   // 4 row-groups of 5 rows
    float b2v[4];
    #pragma unroll
    for (int q = 0; q < 4; ++q) b2v[q] = b2[tx * 4 + q];
    float msum[4] = {0.f, 0.f, 0.f, 0.f};

    __syncthreads();

    for (int ch = 0; ch < 5; ++ch) {   // 5 chunks x 20 particles
        // ---- fc1: h1[p][tid] = relu(x_p . W1[:,tid] + b1)
        #pragma unroll 2
        for (int p = 0; p < 20; ++p) {
            const float4* xr = (const float4*)(xs + (ch * 20 + p) * 64);
            float acc = b1j;
            #pragma unroll
            for (int kq = 0; kq < 16; ++kq) {
                float4 xv = xr[kq];
                acc = fmaf(xv.x, w1c[4*kq+0], acc);
                acc = fmaf(xv.y, w1c[4*kq+1], acc);
                acc = fmaf(xv.z, w1c[4*kq+2], acc);
                acc = fmaf(xv.w, w1c[4*kq+3], acc);
            }
            h1[p][tid] = fmaxf(acc, 0.f);
        }
        __syncthreads();

        // ---- fc2: 20x256 = (20x256)@(256x256), k-tiled by 16
        float acc[5][4];
        #pragma unroll
        for (int r = 0; r < 5; ++r)
            #pragma unroll
            for (int q = 0; q < 4; ++q) acc[r][q] = 0.f;

        for (int kt = 0; kt < 16; ++kt) {
            { // stage W2 rows [kt*16, kt*16+16)
                const float4* src = (const float4*)(w2 + kt * 16 * 256);
                float4* dst = (float4*)w2t;
                for (int i = tid; i < 16 * 256 / 4; i += 256) dst[i] = src[i];
            }
            __syncthreads();
            #pragma unroll
            for (int kk = 0; kk < 16; kk += 4) {
                float4 av[5];
                #pragma unroll
                for (int r = 0; r < 5; ++r)
                    av[r] = *(const float4*)&h1[ty * 5 + r][kt * 16 + kk];
                const float4 w0 = *(const float4*)&w2t[kk + 0][tx * 4];
                const float4 wq1 = *(const float4*)&w2t[kk + 1][tx * 4];
                const float4 wq2 = *(const float4*)&w2t[kk + 2][tx * 4];
                const float4 wq3 = *(const float4*)&w2t[kk + 3][tx * 4];
                #pragma unroll
                for (int r = 0; r < 5; ++r) {
                    const float4 a = av[r];
                    acc[r][0] = fmaf(a.x, w0.x, fmaf(a.y, wq1.x, fmaf(a.z, wq2.x, fmaf(a.w, wq3.x, acc[r][0]))));
                    acc[r][1] = fmaf(a.x, w0.y, fmaf(a.y, wq1.y, fmaf(a.z, wq2.y, fmaf(a.w, wq3.y, acc[r][1]))));
                    acc[r][2] = fmaf(a.x, w0.z, fmaf(a.y, wq1.z, fmaf(a.z, wq2.z, fmaf(a.w, wq3.z, acc[r][2]))));
                    acc[r][3] = fmaf(a.x, w0.w, fmaf(a.y, wq1.w, fmaf(a.z, wq2.w, fmaf(a.w, wq3.w, acc[r][3]))));
                }
            }
            __syncthreads();
        }
        // bias + relu + mean partial accumulate
        #pragma unroll
        for (int r = 0; r < 5; ++r)
            #pragma unroll
            for (int q = 0; q < 4; ++q)
                msum[q] += fmaxf(acc[r][q] + b2v[q], 0.f);
    }

    // cross row-group reduction (reuse w2t storage)
    float* red = &w2t[0][0];
    #pragma unroll
    for (int q = 0; q < 4; ++q) red[ty * 256 + tx * 4 + q] = msum[q];
    __syncthreads();
    float s = red[tid] + red[256 + tid] + red[512 + tid] + red[768 + tid];
    xp[(size_t)b * 256 + tid] = s / 100.0f;
}

// ------------------------------------------------------------------
// Kernel 2: fc3..fc6 fused MLP, 8 rows per block (512 blocks)
// LDS: in0 10240 + h3 16384 + h4 8192 + h5 4096 = 38912B
// ------------------------------------------------------------------
__global__ __launch_bounds__(256) void k_mlp(
    const float* __restrict__ cin, const float* __restrict__ xp,
    const float* __restrict__ w3, const float* __restrict__ b3,
    const float* __restrict__ w4, const float* __restrict__ b4,
    const float* __restrict__ w5, const float* __restrict__ b5,
    const float* __restrict__ w6, const float* __restrict__ b6,
    float* __restrict__ z)
{
    __shared__ float in0[8][320];
    __shared__ float h3[8][512];
    __shared__ float h4[8][256];
    __shared__ float h5[8][128];
    const int tid  = threadIdx.x;
    const int row0 = blockIdx.x * 8;

    // stage input: [c(64) | xp(256)] per row
    for (int i = tid; i < 8 * 16; i += 256) {        // c part, float4
        int r = i >> 4, q = i & 15;
        *(float4*)&in0[r][q * 4] = *(const float4*)&cin[(size_t)(row0 + r) * 64 + q * 4];
    }
    for (int i = tid; i < 8 * 64; i += 256) {        // xp part, float4
        int r = i >> 6, q = i & 63;
        *(float4*)&in0[r][64 + q * 4] = *(const float4*)&xp[(size_t)(row0 + r) * 256 + q * 4];
    }
    __syncthreads();

    // ---- fc3: 320 -> 512, thread covers cols {tid, tid+256}
    {
        float a0[8], a1[8];
        #pragma unroll
        for (int r = 0; r < 8; ++r) { a0[r] = 0.f; a1[r] = 0.f; }
        const int c0 = tid, c1 = tid + 256;
        for (int kq = 0; kq < 80; ++kq) {
            const int k0 = kq * 4;
            float wa0 = w3[(k0+0)*512 + c0], wa1 = w3[(k0+1)*512 + c0];
            float wa2 = w3[(k0+2)*512 + c0], wa3 = w3[(k0+3)*512 + c0];
            float wb0 = w3[(k0+0)*512 + c1], wb1 = w3[(k0+1)*512 + c1];
            float wb2 = w3[(k0+2)*512 + c1], wb3 = w3[(k0+3)*512 + c1];
            #pragma unroll
            for (int r = 0; r < 8; ++r) {
                const float4 a = *(const float4*)&in0[r][k0];
                a0[r] = fmaf(a.x, wa0, fmaf(a.y, wa1, fmaf(a.z, wa2, fmaf(a.w, wa3, a0[r]))));
                a1[r] = fmaf(a.x, wb0, fmaf(a.y, wb1, fmaf(a.z, wb2, fmaf(a.w, wb3, a1[r]))));
            }
        }
        const float bb0 = b3[c0], bb1 = b3[c1];
        #pragma unroll
        for (int r = 0; r < 8; ++r) {
            h3[r][c0] = fmaxf(a0[r] + bb0, 0.f);
            h3[r][c1] = fmaxf(a1[r] + bb1, 0.f);
        }
    }
    __syncthreads();

    // ---- fc4: 512 -> 256, col = tid
    {
        float ac[8];
        #pragma unroll
        for (int r = 0; r < 8; ++r) ac[r] = 0.f;
        for (int kq = 0; kq < 128; ++kq) {
            const int k0 = kq * 4;
            float w0 = w4[(k0+0)*256 + tid], w1v = w4[(k0+1)*256 + tid];
            float w2v = w4[(k0+2)*256 + tid], w3v = w4[(k0+3)*256 + tid];
            #pragma unroll
            for (int r = 0; r < 8; ++r) {
                const float4 a = *(const float4*)&h3[r][k0];
                ac[r] = fmaf(a.x, w0, fmaf(a.y, w1v, fmaf(a.z, w2v, fmaf(a.w, w3v, ac[r]))));
            }
        }
        const float bb = b4[tid];
        #pragma unroll
        for (int r = 0; r < 8; ++r) h4[r][tid] = fmaxf(ac[r] + bb, 0.f);
    }
    __syncthreads();

    // ---- fc5: 256 -> 128, col = tid&127, rows split by tid>>7
    {
        const int c5 = tid & 127, half = tid >> 7;
        float ac[4];
        #pragma unroll
        for (int r = 0; r < 4; ++r) ac[r] = 0.f;
        for (int kq = 0; kq < 64; ++kq) {
            const int k0 = kq * 4;
            float w0 = w5[(k0+0)*128 + c5], w1v = w5[(k0+1)*128 + c5];
            float w2v = w5[(k0+2)*128 + c5], w3v = w5[(k0+3)*128 + c5];
            #pragma unroll
            for (int r = 0; r < 4; ++r) {
                const float4 a = *(const float4*)&h4[half * 4 + r][k0];
                ac[r] = fmaf(a.x, w0, fmaf(a.y, w1v, fmaf(a.z, w2v, fmaf(a.w, w3v, ac[r]))));
            }
        }
        const float bb = b5[c5];
        #pragma unroll
        for (int r = 0; r < 4; ++r) h5[half * 4 + r][c5] = fmaxf(ac[r] + bb, 0.f);
    }
    __syncthreads();

    // ---- fc6: 128 -> 32, col = tid&31, row = tid>>5
    {
        const int c6 = tid & 31, r = tid >> 5;
        float ac = 0.f;
        for (int kq = 0; kq < 32; ++kq) {
            const int k0 = kq * 4;
            float w0 = w6[(k0+0)*32 + c6], w1v = w6[(k0+1)*32 + c6];
            float w2v = w6[(k0+2)*32 + c6], w3v = w6[(k0+3)*32 + c6];
            const float4 a = *(const float4*)&h5[r][k0];
            ac = fmaf(a.x, w0, fmaf(a.y, w1v, fmaf(a.z, w2v, fmaf(a.w, w3v, ac))));
        }
        z[(size_t)(row0 + r) * 32 + c6] = fmaxf(ac + b6[c6], 0.f);
    }
}

// ------------------------------------------------------------------
// Kernel 3: persistent LSTM (6 layers x 24 steps) + fc10 + top-8
// 512 blocks x 8 rows; state lives in LDS, no global sync needed.
// ------------------------------------------------------------------
__global__ __launch_bounds__(256) void k_lstm(
    const float* __restrict__ z,
    const float* __restrict__ hid0, const float* __restrict__ cel0,
    const float* __restrict__ wih, const float* __restrict__ whh,
    const float* __restrict__ bih, const float* __restrict__ bhh,
    const float* __restrict__ w10, const float* __restrict__ b10,
    int* __restrict__ out)
{
    __shared__ float xs[8][32];
    __shared__ float hs[6][8][32];
    __shared__ float cs[6][8][32];
    __shared__ float gates[8][128];
    __shared__ float logits[8][361];
    const int tid  = threadIdx.x;
    const int row0 = blockIdx.x * 8;

    for (int i = tid; i < 8 * 32; i += 256) xs[0][i] = z[(size_t)row0 * 32 + i];
    for (int i = tid; i < 6 * 8 * 32; i += 256) {
        int l = i >> 8, rj = i & 255;
        (&hs[0][0][0])[i] = hid0[(size_t)l * BATCH * 32 + (size_t)row0 * 32 + rj];
        (&cs[0][0][0])[i] = cel0[(size_t)l * BATCH * 32 + (size_t)row0 * 32 + rj];
    }
    __syncthreads();

    const int g  = tid & 127, rg = tid >> 7;       // gate col / row-group
    const int jc = tid & 31,  jr = tid >> 5;       // cell-update mapping
    const int wv = tid >> 6,  lane = tid & 63;     // top-k mapping

    for (int t = 0; t < 24; ++t) {
        for (int l = 0; l < 6; ++l) {
            const float* inp = (l == 0) ? ((t == 0) ? &xs[0][0] : &hs[5][0][0])
                                        : &hs[l - 1][0][0];
            const float* WI = wih + (size_t)l * 32 * 128;
            const float* WH = whh + (size_t)l * 32 * 128;
            const float bsum = bih[l * 128 + g] + bhh[l * 128 + g];
            float acc[4] = {bsum, bsum, bsum, bsum};
            #pragma unroll
            for (int k = 0; k < 32; k += 4) {
                float wi0 = WI[(k+0)*128 + g], wi1 = WI[(k+1)*128 + g];
                float wi2 = WI[(k+2)*128 + g], wi3 = WI[(k+3)*128 + g];
                float wh0 = WH[(k+0)*128 + g], wh1 = WH[(k+1)*128 + g];
                float wh2 = WH[(k+2)*128 + g], wh3 = WH[(k+3)*128 + g];
                #pragma unroll
                for (int rr = 0; rr < 4; ++rr) {
                    const int r = rg * 4 + rr;
                    const float4 ai = *(const float4*)&inp[r * 32 + k];
                    const float4 ah = *(const float4*)&hs[l][r][k];
                    acc[rr] = fmaf(ai.x, wi0, acc[rr]); acc[rr] = fmaf(ai.y, wi1, acc[rr]);
                    acc[rr] = fmaf(ai.z, wi2, acc[rr]); acc[rr] = fmaf(ai.w, wi3, acc[rr]);
                    acc[rr] = fmaf(ah.x, wh0, acc[rr]); acc[rr] = fmaf(ah.y, wh1, acc[rr]);
                    acc[rr] = fmaf(ah.z, wh2, acc[rr]); acc[rr] = fmaf(ah.w, wh3, acc[rr]);
                }
            }
            #pragma unroll
            for (int rr = 0; rr < 4; ++rr) gates[rg * 4 + rr][g] = acc[rr];
            __syncthreads();

            { // cell update (PyTorch LSTM cell math)
                const float gi = gates[jr][jc],      gf = gates[jr][32 + jc];
                const float gg = gates[jr][64 + jc], go = gates[jr][96 + jc];
                const float i_ = 1.f / (1.f + expf(-gi));
                const float f_ = 1.f / (1.f + expf(-gf));
                const float o_ = 1.f / (1.f + expf(-go));
                const float g_ = tanhf(gg);
                const float cn = f_ * cs[l][jr][jc] + i_ * g_;
                cs[l][jr][jc] = cn;
                hs[l][jr][jc] = o_ * tanhf(cn);
            }
            __syncthreads();
        }

        // ---- fc10: logits[r][v] = h5[r] . w10[:,v] + b10[v]
        #pragma unroll
        for (int pass = 0; pass < 2; ++pass) {
            const int v = tid + pass * 256;
            if (v < 361) {
                const float bb = b10[v];
                float a8[8];
                #pragma unroll
                for (int r = 0; r < 8; ++r) a8[r] = bb;
                #pragma unroll
                for (int k = 0; k < 32; k += 4) {
                    float w0 = w10[(k+0)*361 + v], w1v = w10[(k+1)*361 + v];
                    float w2v = w10[(k+2)*361 + v], w3v = w10[(k+3)*361 + v];
                    #pragma unroll
                    for (int r = 0; r < 8; ++r) {
                        const float4 a = *(const float4*)&hs[5][r][k];
                        a8[r] = fmaf(a.x, w0, fmaf(a.y, w1v, fmaf(a.z, w2v, fmaf(a.w, w3v, a8[r]))));
                    }
                }
                #pragma unroll
                for (int r = 0; r < 8; ++r) logits[r][v] = a8[r];
            }
        }
        __syncthreads();

        // ---- top-8 per row; one wave handles 2 rows.
        // jax.lax.top_k: values descending, ties -> lower index first.
        for (int rr = 0; rr < 2; ++rr) {
            const int r = wv * 2 + rr;
            float val[6];
            #pragma unroll
            for (int s = 0; s < 6; ++s) {
                const int v = lane + 64 * s;
                val[s] = (v < 361) ? logits[r][v] : -3.4e38f;
            }
            unsigned msk = 0x3Fu;
            const int rowg = row0 + r;
            for (int sel = 0; sel < 8; ++sel) {
                float bv = -3.4e38f; int bi = 0x7FFFFFFF;
                #pragma unroll
                for (int s = 0; s < 6; ++s) {
                    if (msk & (1u << s)) {
                        const float v2 = val[s]; const int i2 = lane + 64 * s;
                        if (v2 > bv || (v2 == bv && i2 < bi)) { bv = v2; bi = i2; }
                    }
                }
                #pragma unroll
                for (int off = 32; off >= 1; off >>= 1) {
                    const float ov = __shfl_xor(bv, off, 64);
                    const int   oi = __shfl_xor(bi, off, 64);
                    if (ov > bv || (ov == bv && oi < bi)) { bv = ov; bi = oi; }
                }
                if ((bi & 63) == lane) msk &= ~(1u << (bi >> 6));
                if (lane == 0) out[(size_t)rowg * 192 + t * 8 + sel] = bi;
            }
        }
        __syncthreads();
    }
}

// ------------------------------------------------------------------
extern "C" void kernel_launch(void* const* d_in, const int* in_sizes, int n_in,
                              void* d_out, int out_size, void* d_ws, size_t ws_size,
                              hipStream_t stream) {
    const float* cin  = (const float*)d_in[0];
    const float* x    = (const float*)d_in[1];
    const float* hid0 = (const float*)d_in[2];
    const float* cel0 = (const float*)d_in[3];
    const float* w1 = (const float*)d_in[4];  const float* b1 = (const float*)d_in[5];
    const float* w2 = (const float*)d_in[6];  const float* b2 = (const float*)d_in[7];
    const float* w3 = (const float*)d_in[8];  const float* b3 = (const float*)d_in[9];
    const float* w4 = (const float*)d_in[10]; const float* b4 = (const float*)d_in[11];
    const float* w5 = (const float*)d_in[12]; const float* b5 = (const float*)d_in[13];
    const float* w6 = (const float*)d_in[14]; const float* b6 = (const float*)d_in[15];
    const float* wih = (const float*)d_in[16]; const float* whh = (const float*)d_in[17];
    const float* bih = (const float*)d_in[18]; const float* bhh = (const float*)d_in[19];
    const float* w10 = (const float*)d_in[20]; const float* b10 = (const float*)d_in[21];

    float* xp = (float*)d_ws;                       // 4096 x 256
    float* zz = xp + (size_t)BATCH * 256;           // 4096 x 32
    int*   out = (int*)d_out;

    k_encoder<<<BATCH, 256, 0, stream>>>(x, w1, b1, w2, b2, xp);
    k_mlp<<<BATCH / 8, 256, 0, stream>>>(cin, xp, w3, b3, w4, b4, w5, b5, w6, b6, zz);
    k_lstm<<<BATCH / 8, 256, 0, stream>>>(zz, hid0, cel0, wih, whh, bih, bhh, w10, b10, out);
}

// Round 2
// 2627.626 us; speedup vs baseline: 1.2938x; 1.2938x over previous
//
#include <hip/hip_runtime.h>
#include <math.h>

#define BATCH 4096
#define NPART 100
#define PSZ   64

// ------------------------------------------------------------------
// Kernel 1: particle encoder: relu(relu(x@W1+b1)@W2+b2).mean(particles)
// One block per batch element, 256 threads.
// v2: LDS holds only h1 (32KB) -> 3 blocks/CU (launch_bounds 256,3).
//     W2 read directly from global (L1/L2-hot), x rows via uniform
//     broadcast loads. 8 barriers/block (was 160). Register tile 4x8.
// ------------------------------------------------------------------
__global__ __launch_bounds__(256, 3) void k_encoder(
    const float* __restrict__ x,
    const float* __restrict__ w1, const float* __restrict__ b1,
    const float* __restrict__ w2, const float* __restrict__ b2,
    float* __restrict__ xp)
{
    __shared__ float h1[32][256];     // one 32-particle chunk of fc1 output
    const int tid = threadIdx.x;
    const int b   = blockIdx.x;

    // cache W1 column `tid` in registers (reused for all 100 particles)
    float w1c[64];
    #pragma unroll
    for (int k = 0; k < 64; ++k) w1c[k] = w1[k * 256 + tid];
    const float b1j = b1[tid];

    const int tx = tid & 31;   // col group: cols tx*8 .. tx*8+7
    const int ty = tid >> 5;   // row group: rows ty*4 .. ty*4+3 (of chunk)
    const float4 b2a = *(const float4*)&b2[tx * 8];
    const float4 b2b = *(const float4*)&b2[tx * 8 + 4];
    float msum[8] = {0.f,0.f,0.f,0.f,0.f,0.f,0.f,0.f};

    const float* xb  = x + (size_t)b * (NPART * PSZ);
    const float* w2p = w2 + tx * 8;

    for (int ch = 0; ch < 4; ++ch) {      // 4 chunks x 32 particles (last: 4 valid)
        const int rbase = ch * 32;
        const int rows  = (rbase + 32 <= NPART) ? 32 : (NPART - rbase);

        // ---- fc1: h1[p][tid] = relu(x_p . W1[:,tid] + b1)
        #pragma unroll 2
        for (int p = 0; p < rows; ++p) {
            const float4* xr = (const float4*)(xb + (rbase + p) * 64);
            float acc = b1j;
            #pragma unroll
            for (int kq = 0; kq < 16; ++kq) {
                const float4 xv = xr[kq];
                acc = fmaf(xv.x, w1c[4*kq+0], acc);
                acc = fmaf(xv.y, w1c[4*kq+1], acc);
                acc = fmaf(xv.z, w1c[4*kq+2], acc);
                acc = fmaf(xv.w, w1c[4*kq+3], acc);
            }
            h1[p][tid] = fmaxf(acc, 0.f);
        }
        __syncthreads();

        // ---- fc2: acc[4 rows][8 cols]; A from LDS, B streamed from global
        float acc[4][8];
        #pragma unroll
        for (int r = 0; r < 4; ++r)
            #pragma unroll
            for (int q = 0; q < 8; ++q) acc[r][q] = 0.f;

        #pragma unroll 2
        for (int k0 = 0; k0 < 256; k0 += 4) {
            float4 bv0[4], bv1[4];
            #pragma unroll
            for (int kk = 0; kk < 4; ++kk) {
                bv0[kk] = *(const float4*)(w2p + (k0 + kk) * 256);
                bv1[kk] = *(const float4*)(w2p + (k0 + kk) * 256 + 4);
            }
            float4 av[4];
            #pragma unroll
            for (int r = 0; r < 4; ++r)
                av[r] = *(const float4*)&h1[ty * 4 + r][k0];
            #pragma unroll
            for (int r = 0; r < 4; ++r) {
                const float a0 = av[r].x, a1 = av[r].y, a2 = av[r].z, a3 = av[r].w;
                acc[r][0] = fmaf(a0, bv0[0].x, fmaf(a1, bv0[1].x, fmaf(a2, bv0[2].x, fmaf(a3, bv0[3].x, acc[r][0]))));
                acc[r][1] = fmaf(a0, bv0[0].y, fmaf(a1, bv0[1].y, fmaf(a2, bv0[2].y, fmaf(a3, bv0[3].y, acc[r][1]))));
                acc[r][2] = fmaf(a0, bv0[0].z, fmaf(a1, bv0[1].z, fmaf(a2, bv0[2].z, fmaf(a3, bv0[3].z, acc[r][2]))));
                acc[r][3] = fmaf(a0, bv0[0].w, fmaf(a1, bv0[1].w, fmaf(a2, bv0[2].w, fmaf(a3, bv0[3].w, acc[r][3]))));
                acc[r][4] = fmaf(a0, bv1[0].x, fmaf(a1, bv1[1].x, fmaf(a2, bv1[2].x, fmaf(a3, bv1[3].x, acc[r][4]))));
                acc[r][5] = fmaf(a0, bv1[0].y, fmaf(a1, bv1[1].y, fmaf(a2, bv1[2].y, fmaf(a3, bv1[3].y, acc[r][5]))));
                acc[r][6] = fmaf(a0, bv1[0].z, fmaf(a1, bv1[1].z, fmaf(a2, bv1[2].z, fmaf(a3, bv1[3].z, acc[r][6]))));
                acc[r][7] = fmaf(a0, bv1[0].w, fmaf(a1, bv1[1].w, fmaf(a2, bv1[2].w, fmaf(a3, bv1[3].w, acc[r][7]))));
            }
        }

        // bias + relu + masked mean accumulate (rows >= 100 are padding)
        #pragma unroll
        for (int r = 0; r < 4; ++r) {
            const int grow = rbase + ty * 4 + r;
            if (grow < NPART) {
                msum[0] += fmaxf(acc[r][0] + b2a.x, 0.f);
                msum[1] += fmaxf(acc[r][1] + b2a.y, 0.f);
                msum[2] += fmaxf(acc[r][2] + b2a.z, 0.f);
                msum[3] += fmaxf(acc[r][3] + b2a.w, 0.f);
                msum[4] += fmaxf(acc[r][4] + b2b.x, 0.f);
                msum[5] += fmaxf(acc[r][5] + b2b.y, 0.f);
                msum[6] += fmaxf(acc[r][6] + b2b.z, 0.f);
                msum[7] += fmaxf(acc[r][7] + b2b.w, 0.f);
            }
        }
        __syncthreads();   // protect h1 for next chunk's fc1 writes
    }

    // cross row-group reduction (reuse h1 storage)
    float* red = &h1[0][0];
    #pragma unroll
    for (int q = 0; q < 8; ++q) red[ty * 256 + tx * 8 + q] = msum[q];
    __syncthreads();
    float s = 0.f;
    #pragma unroll
    for (int g = 0; g < 8; ++g) s += red[g * 256 + tid];
    xp[(size_t)b * 256 + tid] = s / 100.0f;
}

// ------------------------------------------------------------------
// Kernel 2: fc3..fc6 fused MLP, 8 rows per block (512 blocks)
// ------------------------------------------------------------------
__global__ __launch_bounds__(256) void k_mlp(
    const float* __restrict__ cin, const float* __restrict__ xp,
    const float* __restrict__ w3, const float* __restrict__ b3,
    const float* __restrict__ w4, const float* __restrict__ b4,
    const float* __restrict__ w5, const float* __restrict__ b5,
    const float* __restrict__ w6, const float* __restrict__ b6,
    float* __restrict__ z)
{
    __shared__ float in0[8][320];
    __shared__ float h3[8][512];
    __shared__ float h4[8][256];
    __shared__ float h5[8][128];
    const int tid  = threadIdx.x;
    const int row0 = blockIdx.x * 8;

    for (int i = tid; i < 8 * 16; i += 256) {        // c part, float4
        int r = i >> 4, q = i & 15;
        *(float4*)&in0[r][q * 4] = *(const float4*)&cin[(size_t)(row0 + r) * 64 + q * 4];
    }
    for (int i = tid; i < 8 * 64; i += 256) {        // xp part, float4
        int r = i >> 6, q = i & 63;
        *(float4*)&in0[r][64 + q * 4] = *(const float4*)&xp[(size_t)(row0 + r) * 256 + q * 4];
    }
    __syncthreads();

    // ---- fc3: 320 -> 512, thread covers cols {tid, tid+256}
    {
        float a0[8], a1[8];
        #pragma unroll
        for (int r = 0; r < 8; ++r) { a0[r] = 0.f; a1[r] = 0.f; }
        const int c0 = tid, c1 = tid + 256;
        for (int kq = 0; kq < 80; ++kq) {
            const int k0 = kq * 4;
            float wa0 = w3[(k0+0)*512 + c0], wa1 = w3[(k0+1)*512 + c0];
            float wa2 = w3[(k0+2)*512 + c0], wa3 = w3[(k0+3)*512 + c0];
            float wb0 = w3[(k0+0)*512 + c1], wb1 = w3[(k0+1)*512 + c1];
            float wb2 = w3[(k0+2)*512 + c1], wb3 = w3[(k0+3)*512 + c1];
            #pragma unroll
            for (int r = 0; r < 8; ++r) {
                const float4 a = *(const float4*)&in0[r][k0];
                a0[r] = fmaf(a.x, wa0, fmaf(a.y, wa1, fmaf(a.z, wa2, fmaf(a.w, wa3, a0[r]))));
                a1[r] = fmaf(a.x, wb0, fmaf(a.y, wb1, fmaf(a.z, wb2, fmaf(a.w, wb3, a1[r]))));
            }
        }
        const float bb0 = b3[c0], bb1 = b3[c1];
        #pragma unroll
        for (int r = 0; r < 8; ++r) {
            h3[r][c0] = fmaxf(a0[r] + bb0, 0.f);
            h3[r][c1] = fmaxf(a1[r] + bb1, 0.f);
        }
    }
    __syncthreads();

    // ---- fc4: 512 -> 256, col = tid
    {
        float ac[8];
        #pragma unroll
        for (int r = 0; r < 8; ++r) ac[r] = 0.f;
        for (int kq = 0; kq < 128; ++kq) {
            const int k0 = kq * 4;
            float w0 = w4[(k0+0)*256 + tid], w1v = w4[(k0+1)*256 + tid];
            float w2v = w4[(k0+2)*256 + tid], w3v = w4[(k0+3)*256 + tid];
            #pragma unroll
            for (int r = 0; r < 8; ++r) {
                const float4 a = *(const float4*)&h3[r][k0];
                ac[r] = fmaf(a.x, w0, fmaf(a.y, w1v, fmaf(a.z, w2v, fmaf(a.w, w3v, ac[r]))));
            }
        }
        const float bb = b4[tid];
        #pragma unroll
        for (int r = 0; r < 8; ++r) h4[r][tid] = fmaxf(ac[r] + bb, 0.f);
    }
    __syncthreads();

    // ---- fc5: 256 -> 128
    {
        const int c5 = tid & 127, half = tid >> 7;
        float ac[4];
        #pragma unroll
        for (int r = 0; r < 4; ++r) ac[r] = 0.f;
        for (int kq = 0; kq < 64; ++kq) {
            const int k0 = kq * 4;
            float w0 = w5[(k0+0)*128 + c5], w1v = w5[(k0+1)*128 + c5];
            float w2v = w5[(k0+2)*128 + c5], w3v = w5[(k0+3)*128 + c5];
            #pragma unroll
            for (int r = 0; r < 4; ++r) {
                const float4 a = *(const float4*)&h4[half * 4 + r][k0];
                ac[r] = fmaf(a.x, w0, fmaf(a.y, w1v, fmaf(a.z, w2v, fmaf(a.w, w3v, ac[r]))));
            }
        }
        const float bb = b5[c5];
        #pragma unroll
        for (int r = 0; r < 4; ++r) h5[half * 4 + r][c5] = fmaxf(ac[r] + bb, 0.f);
    }
    __syncthreads();

    // ---- fc6: 128 -> 32
    {
        const int c6 = tid & 31, r = tid >> 5;
        float ac = 0.f;
        for (int kq = 0; kq < 32; ++kq) {
            const int k0 = kq * 4;
            float w0 = w6[(k0+0)*32 + c6], w1v = w6[(k0+1)*32 + c6];
            float w2v = w6[(k0+2)*32 + c6], w3v = w6[(k0+3)*32 + c6];
            const float4 a = *(const float4*)&h5[r][k0];
            ac = fmaf(a.x, w0, fmaf(a.y, w1v, fmaf(a.z, w2v, fmaf(a.w, w3v, ac))));
        }
        z[(size_t)(row0 + r) * 32 + c6] = fmaxf(ac + b6[c6], 0.f);
    }
}

// ------------------------------------------------------------------
// Kernel 3: persistent LSTM (6 layers x 24 steps) + fc10 + top-8
// ------------------------------------------------------------------
__global__ __launch_bounds__(256) void k_lstm(
    const float* __restrict__ z,
    const float* __restrict__ hid0, const float* __restrict__ cel0,
    const float* __restrict__ wih, const float* __restrict__ whh,
    const float* __restrict__ bih, const float* __restrict__ bhh,
    const float* __restrict__ w10, const float* __restrict__ b10,
    int* __restrict__ out)
{
    __shared__ float xs[8][32];
    __shared__ float hs[6][8][32];
    __shared__ float cs[6][8][32];
    __shared__ float gates[8][128];
    __shared__ float logits[8][361];
    const int tid  = threadIdx.x;
    const int row0 = blockIdx.x * 8;

    for (int i = tid; i < 8 * 32; i += 256) xs[0][i] = z[(size_t)row0 * 32 + i];
    for (int i = tid; i < 6 * 8 * 32; i += 256) {
        int l = i >> 8, rj = i & 255;
        (&hs[0][0][0])[i] = hid0[(size_t)l * BATCH * 32 + (size_t)row0 * 32 + rj];
        (&cs[0][0][0])[i] = cel0[(size_t)l * BATCH * 32 + (size_t)row0 * 32 + rj];
    }
    __syncthreads();

    const int g  = tid & 127, rg = tid >> 7;
    const int jc = tid & 31,  jr = tid >> 5;
    const int wv = tid >> 6,  lane = tid & 63;

    for (int t = 0; t < 24; ++t) {
        for (int l = 0; l < 6; ++l) {
            const float* inp = (l == 0) ? ((t == 0) ? &xs[0][0] : &hs[5][0][0])
                                        : &hs[l - 1][0][0];
            const float* WI = wih + (size_t)l * 32 * 128;
            const float* WH = whh + (size_t)l * 32 * 128;
            const float bsum = bih[l * 128 + g] + bhh[l * 128 + g];
            float acc[4] = {bsum, bsum, bsum, bsum};
            #pragma unroll
            for (int k = 0; k < 32; k += 4) {
                float wi0 = WI[(k+0)*128 + g], wi1 = WI[(k+1)*128 + g];
                float wi2 = WI[(k+2)*128 + g], wi3 = WI[(k+3)*128 + g];
                float wh0 = WH[(k+0)*128 + g], wh1 = WH[(k+1)*128 + g];
                float wh2 = WH[(k+2)*128 + g], wh3 = WH[(k+3)*128 + g];
                #pragma unroll
                for (int rr = 0; rr < 4; ++rr) {
                    const int r = rg * 4 + rr;
                    const float4 ai = *(const float4*)&inp[r * 32 + k];
                    const float4 ah = *(const float4*)&hs[l][r][k];
                    acc[rr] = fmaf(ai.x, wi0, acc[rr]); acc[rr] = fmaf(ai.y, wi1, acc[rr]);
                    acc[rr] = fmaf(ai.z, wi2, acc[rr]); acc[rr] = fmaf(ai.w, wi3, acc[rr]);
                    acc[rr] = fmaf(ah.x, wh0, acc[rr]); acc[rr] = fmaf(ah.y, wh1, acc[rr]);
                    acc[rr] = fmaf(ah.z, wh2, acc[rr]); acc[rr] = fmaf(ah.w, wh3, acc[rr]);
                }
            }
            #pragma unroll
            for (int rr = 0; rr < 4; ++rr) gates[rg * 4 + rr][g] = acc[rr];
            __syncthreads();

            {
                const float gi = gates[jr][jc],      gf = gates[jr][32 + jc];
                const float gg = gates[jr][64 + jc], go = gates[jr][96 + jc];
                const float i_ = 1.f / (1.f + expf(-gi));
                const float f_ = 1.f / (1.f + expf(-gf));
                const float o_ = 1.f / (1.f + expf(-go));
                const float g_ = tanhf(gg);
                const float cn = f_ * cs[l][jr][jc] + i_ * g_;
                cs[l][jr][jc] = cn;
                hs[l][jr][jc] = o_ * tanhf(cn);
            }
            __syncthreads();
        }

        // ---- fc10
        #pragma unroll
        for (int pass = 0; pass < 2; ++pass) {
            const int v = tid + pass * 256;
            if (v < 361) {
                const float bb = b10[v];
                float a8[8];
                #pragma unroll
                for (int r = 0; r < 8; ++r) a8[r] = bb;
                #pragma unroll
                for (int k = 0; k < 32; k += 4) {
                    float w0 = w10[(k+0)*361 + v], w1v = w10[(k+1)*361 + v];
                    float w2v = w10[(k+2)*361 + v], w3v = w10[(k+3)*361 + v];
                    #pragma unroll
                    for (int r = 0; r < 8; ++r) {
                        const float4 a = *(const float4*)&hs[5][r][k];
                        a8[r] = fmaf(a.x, w0, fmaf(a.y, w1v, fmaf(a.z, w2v, fmaf(a.w, w3v, a8[r]))));
                    }
                }
                #pragma unroll
                for (int r = 0; r < 8; ++r) logits[r][v] = a8[r];
            }
        }
        __syncthreads();

        // ---- top-8 per row; one wave handles 2 rows.
        for (int rr = 0; rr < 2; ++rr) {
            const int r = wv * 2 + rr;
            float val[6];
            #pragma unroll
            for (int s = 0; s < 6; ++s) {
                const int v = lane + 64 * s;
                val[s] = (v < 361) ? logits[r][v] : -3.4e38f;
            }
            unsigned msk = 0x3Fu;
            const int rowg = row0 + r;
            for (int sel = 0; sel < 8; ++sel) {
                float bv = -3.4e38f; int bi = 0x7FFFFFFF;
                #pragma unroll
                for (int s = 0; s < 6; ++s) {
                    if (msk & (1u << s)) {
                        const float v2 = val[s]; const int i2 = lane + 64 * s;
                        if (v2 > bv || (v2 == bv && i2 < bi)) { bv = v2; bi = i2; }
                    }
                }
                #pragma unroll
                for (int off = 32; off >= 1; off >>= 1) {
                    const float ov = __shfl_xor(bv, off, 64);
                    const int   oi = __shfl_xor(bi, off, 64);
                    if (ov > bv || (ov == bv && oi < bi)) { bv = ov; bi = oi; }
                }
                if ((bi & 63) == lane) msk &= ~(1u << (bi >> 6));
                if (lane == 0) out[(size_t)rowg * 192 + t * 8 + sel] = bi;
            }
        }
        __syncthreads();
    }
}

// ------------------------------------------------------------------
extern "C" void kernel_launch(void* const* d_in, const int* in_sizes, int n_in,
                              void* d_out, int out_size, void* d_ws, size_t ws_size,
                              hipStream_t stream) {
    const float* cin  = (const float*)d_in[0];
    const float* x    = (const float*)d_in[1];
    const float* hid0 = (const float*)d_in[2];
    const float* cel0 = (const float*)d_in[3];
    const float* w1 = (const float*)d_in[4];  const float* b1 = (const float*)d_in[5];
    const float* w2 = (const float*)d_in[6];  const float* b2 = (const float*)d_in[7];
    const float* w3 = (const float*)d_in[8];  const float* b3 = (const float*)d_in[9];
    const float* w4 = (const float*)d_in[10]; const float* b4 = (const float*)d_in[11];
    const float* w5 = (const float*)d_in[12]; const float* b5 = (const float*)d_in[13];
    const float* w6 = (const float*)d_in[14]; const float* b6 = (const float*)d_in[15];
    const float* wih = (const float*)d_in[16]; const float* whh = (const float*)d_in[17];
    const float* bih = (const float*)d_in[18]; const float* bhh = (const float*)d_in[19];
    const float* w10 = (const float*)d_in[20]; const float* b10 = (const float*)d_in[21];

    float* xp = (float*)d_ws;                       // 4096 x 256
    float* zz = xp + (size_t)BATCH * 256;           // 4096 x 32
    int*   out = (int*)d_out;

    k_encoder<<<BATCH, 256, 0, stream>>>(x, w1, b1, w2, b2, xp);
    k_mlp<<<BATCH / 8, 256, 0, stream>>>(cin, xp, w3, b3, w4, b4, w5, b5, w6, b6, zz);
    k_lstm<<<BATCH / 8, 256, 0, stream>>>(zz, hid0, cel0, wih, whh, bih, bhh, w10, b10, out);
}

// Round 3
// 2310.423 us; speedup vs baseline: 1.4714x; 1.1373x over previous
//
#include <hip/hip_runtime.h>
#include <math.h>

#define BATCH 4096
#define NPART 100
#define PSZ   64

__device__ __forceinline__ void fma4(float4& d, const float s, const float4 v) {
    d.x = fmaf(s, v.x, d.x); d.y = fmaf(s, v.y, d.y);
    d.z = fmaf(s, v.z, d.z); d.w = fmaf(s, v.w, d.w);
}
__device__ __forceinline__ float4 addrelu4(const float4 a, const float4 b) {
    return make_float4(fmaxf(a.x + b.x, 0.f), fmaxf(a.y + b.y, 0.f),
                       fmaxf(a.z + b.z, 0.f), fmaxf(a.w + b.w, 0.f));
}

// ------------------------------------------------------------------
// Encoder chunk worker. Lane tile: NRR rows x 8 cols. Rows of the chunk
// assigned {rg, rg+8, rg+16, rg+24} so LDS b128 reads are conflict-free
// (row stride 260 dwords -> bank offset +4 per rg). B (W1/W2) streamed
// from global: each wave owns a 64-col slice -> W read once/chunk/block.
// ------------------------------------------------------------------
template<int NRR, int ROWS>
__device__ __forceinline__ void enc_chunk(
    const float* __restrict__ xb, const int rbase,
    const float* __restrict__ w1c, const float* __restrict__ w2c,
    float* __restrict__ h1s, float* __restrict__ xss,
    const int tid, const int rg, const int col0,
    const float4 b1a, const float4 b1b, const float4 b2a, const float4 b2b,
    float* msum)
{
    // stage x chunk (ROWS x 64) into LDS, stride 68 dwords
    for (int i = tid; i < ROWS * 16; i += 256) {
        const int r = i >> 4, q = (i & 15) * 4;
        *(float4*)&xss[r * 68 + q] = *(const float4*)(xb + (size_t)(rbase + r) * 64 + q);
    }
    __syncthreads();

    // ---- fc1: h1 = relu(x @ W1 + b1), K=64, B from global (L1/L2-hot)
    float4 a0[NRR], a1[NRR];
    #pragma unroll
    for (int rr = 0; rr < NRR; ++rr) {
        a0[rr] = make_float4(0.f, 0.f, 0.f, 0.f);
        a1[rr] = make_float4(0.f, 0.f, 0.f, 0.f);
    }
    #pragma unroll 2
    for (int k0 = 0; k0 < 64; k0 += 4) {
        float4 bva[4], bvb[4];
        #pragma unroll
        for (int kk = 0; kk < 4; ++kk) {
            bva[kk] = *(const float4*)(w1c + (k0 + kk) * 256);
            bvb[kk] = *(const float4*)(w1c + (k0 + kk) * 256 + 4);
        }
        #pragma unroll
        for (int rr = 0; rr < NRR; ++rr) {
            const float4 a = *(const float4*)&xss[(rg + 8 * rr) * 68 + k0];
            fma4(a0[rr], a.x, bva[0]); fma4(a0[rr], a.y, bva[1]);
            fma4(a0[rr], a.z, bva[2]); fma4(a0[rr], a.w, bva[3]);
            fma4(a1[rr], a.x, bvb[0]); fma4(a1[rr], a.y, bvb[1]);
            fma4(a1[rr], a.z, bvb[2]); fma4(a1[rr], a.w, bvb[3]);
        }
    }
    #pragma unroll
    for (int rr = 0; rr < NRR; ++rr) {
        const int r = rg + 8 * rr;
        *(float4*)&h1s[r * 260 + col0]     = addrelu4(a0[rr], b1a);
        *(float4*)&h1s[r * 260 + col0 + 4] = addrelu4(a1[rr], b1b);
    }
    __syncthreads();

    // ---- fc2: K=256, A from LDS (conflict-free), B from global
    float4 c0[NRR], c1[NRR];
    #pragma unroll
    for (int rr = 0; rr < NRR; ++rr) {
        c0[rr] = make_float4(0.f, 0.f, 0.f, 0.f);
        c1[rr] = make_float4(0.f, 0.f, 0.f, 0.f);
    }
    #pragma unroll 2
    for (int k0 = 0; k0 < 256; k0 += 4) {
        float4 bva[4], bvb[4];
        #pragma unroll
        for (int kk = 0; kk < 4; ++kk) {
            bva[kk] = *(const float4*)(w2c + (k0 + kk) * 256);
            bvb[kk] = *(const float4*)(w2c + (k0 + kk) * 256 + 4);
        }
        #pragma unroll
        for (int rr = 0; rr < NRR; ++rr) {
            const float4 a = *(const float4*)&h1s[(rg + 8 * rr) * 260 + k0];
            fma4(c0[rr], a.x, bva[0]); fma4(c0[rr], a.y, bva[1]);
            fma4(c0[rr], a.z, bva[2]); fma4(c0[rr], a.w, bva[3]);
            fma4(c1[rr], a.x, bvb[0]); fma4(c1[rr], a.y, bvb[1]);
            fma4(c1[rr], a.z, bvb[2]); fma4(c1[rr], a.w, bvb[3]);
        }
    }
    #pragma unroll
    for (int rr = 0; rr < NRR; ++rr) {
        if (NRR == 4 || rg < 4) {   // full chunks: all rows valid; tail: rows 96..99
            msum[0] += fmaxf(c0[rr].x + b2a.x, 0.f);
            msum[1] += fmaxf(c0[rr].y + b2a.y, 0.f);
            msum[2] += fmaxf(c0[rr].z + b2a.z, 0.f);
            msum[3] += fmaxf(c0[rr].w + b2a.w, 0.f);
            msum[4] += fmaxf(c1[rr].x + b2b.x, 0.f);
            msum[5] += fmaxf(c1[rr].y + b2b.y, 0.f);
            msum[6] += fmaxf(c1[rr].z + b2b.z, 0.f);
            msum[7] += fmaxf(c1[rr].w + b2b.w, 0.f);
        }
    }
    __syncthreads();
}

// ------------------------------------------------------------------
// Kernel 1: particle encoder, one block per batch element, 256 threads.
// v3: no register-resident W1 (was spilling 424MB to scratch); both fc1
// and fc2 are wave-col-sliced GEMMs with B streamed from global exactly
// once per chunk per block. Slim tail chunk (4 valid rows).
// ------------------------------------------------------------------
__global__ __launch_bounds__(256) void k_encoder(
    const float* __restrict__ x,
    const float* __restrict__ w1, const float* __restrict__ b1,
    const float* __restrict__ w2, const float* __restrict__ b2,
    float* __restrict__ xp)
{
    __shared__ __align__(16) float h1s[32 * 260];   // 33280 B, padded stride
    __shared__ __align__(16) float xss[32 * 68];    //  8704 B, padded stride
    const int tid  = threadIdx.x;
    const int b    = blockIdx.x;
    const int lane = tid & 63;
    const int wv   = tid >> 6;          // wave 0..3 -> 64-col slice
    const int cg   = lane & 7;          // col-group (8 cols)
    const int rg   = lane >> 3;         // row-group 0..7
    const int col0 = wv * 64 + cg * 8;

    const float* xb  = x + (size_t)b * (NPART * PSZ);
    const float* w1c = w1 + col0;
    const float* w2c = w2 + col0;
    const float4 b1a = *(const float4*)&b1[col0];
    const float4 b1b = *(const float4*)&b1[col0 + 4];
    const float4 b2a = *(const float4*)&b2[col0];
    const float4 b2b = *(const float4*)&b2[col0 + 4];

    float msum[8] = {0.f,0.f,0.f,0.f,0.f,0.f,0.f,0.f};

    enc_chunk<4,32>(xb,  0, w1c, w2c, h1s, xss, tid, rg, col0, b1a, b1b, b2a, b2b, msum);
    enc_chunk<4,32>(xb, 32, w1c, w2c, h1s, xss, tid, rg, col0, b1a, b1b, b2a, b2b, msum);
    enc_chunk<4,32>(xb, 64, w1c, w2c, h1s, xss, tid, rg, col0, b1a, b1b, b2a, b2b, msum);
    enc_chunk<1, 4>(xb, 96, w1c, w2c, h1s, xss, tid, rg, col0, b1a, b1b, b2a, b2b, msum);

    // reduce over the 8 row-groups via wave butterfly (lane bits 3,4,5)
    #pragma unroll
    for (int q = 0; q < 8; ++q) {
        msum[q] += __shfl_xor(msum[q], 8, 64);
        msum[q] += __shfl_xor(msum[q], 16, 64);
        msum[q] += __shfl_xor(msum[q], 32, 64);
    }
    if (rg == 0) {
        float4 o0 = make_float4(msum[0] / 100.f, msum[1] / 100.f,
                                msum[2] / 100.f, msum[3] / 100.f);
        float4 o1 = make_float4(msum[4] / 100.f, msum[5] / 100.f,
                                msum[6] / 100.f, msum[7] / 100.f);
        *(float4*)&xp[(size_t)b * 256 + col0]     = o0;
        *(float4*)&xp[(size_t)b * 256 + col0 + 4] = o1;
    }
}

// ------------------------------------------------------------------
// Kernel 2: fc3..fc6 fused MLP, 8 rows per block (512 blocks)
// ------------------------------------------------------------------
__global__ __launch_bounds__(256) void k_mlp(
    const float* __restrict__ cin, const float* __restrict__ xp,
    const float* __restrict__ w3, const float* __restrict__ b3,
    const float* __restrict__ w4, const float* __restrict__ b4,
    const float* __restrict__ w5, const float* __restrict__ b5,
    const float* __restrict__ w6, const float* __restrict__ b6,
    float* __restrict__ z)
{
    __shared__ float in0[8][320];
    __shared__ float h3[8][512];
    __shared__ float h4[8][256];
    __shared__ float h5[8][128];
    const int tid  = threadIdx.x;
    const int row0 = blockIdx.x * 8;

    for (int i = tid; i < 8 * 16; i += 256) {
        int r = i >> 4, q = i & 15;
        *(float4*)&in0[r][q * 4] = *(const float4*)&cin[(size_t)(row0 + r) * 64 + q * 4];
    }
    for (int i = tid; i < 8 * 64; i += 256) {
        int r = i >> 6, q = i & 63;
        *(float4*)&in0[r][64 + q * 4] = *(const float4*)&xp[(size_t)(row0 + r) * 256 + q * 4];
    }
    __syncthreads();

    // ---- fc3: 320 -> 512, thread covers cols {tid, tid+256}
    {
        float a0[8], a1[8];
        #pragma unroll
        for (int r = 0; r < 8; ++r) { a0[r] = 0.f; a1[r] = 0.f; }
        const int c0 = tid, c1 = tid + 256;
        for (int kq = 0; kq < 80; ++kq) {
            const int k0 = kq * 4;
            float wa0 = w3[(k0+0)*512 + c0], wa1 = w3[(k0+1)*512 + c0];
            float wa2 = w3[(k0+2)*512 + c0], wa3 = w3[(k0+3)*512 + c0];
            float wb0 = w3[(k0+0)*512 + c1], wb1 = w3[(k0+1)*512 + c1];
            float wb2 = w3[(k0+2)*512 + c1], wb3 = w3[(k0+3)*512 + c1];
            #pragma unroll
            for (int r = 0; r < 8; ++r) {
                const float4 a = *(const float4*)&in0[r][k0];
                a0[r] = fmaf(a.x, wa0, fmaf(a.y, wa1, fmaf(a.z, wa2, fmaf(a.w, wa3, a0[r]))));
                a1[r] = fmaf(a.x, wb0, fmaf(a.y, wb1, fmaf(a.z, wb2, fmaf(a.w, wb3, a1[r]))));
            }
        }
        const float bb0 = b3[c0], bb1 = b3[c1];
        #pragma unroll
        for (int r = 0; r < 8; ++r) {
            h3[r][c0] = fmaxf(a0[r] + bb0, 0.f);
            h3[r][c1] = fmaxf(a1[r] + bb1, 0.f);
        }
    }
    __syncthreads();

    // ---- fc4: 512 -> 256, col = tid
    {
        float ac[8];
        #pragma unroll
        for (int r = 0; r < 8; ++r) ac[r] = 0.f;
        for (int kq = 0; kq < 128; ++kq) {
            const int k0 = kq * 4;
            float w0 = w4[(k0+0)*256 + tid], w1v = w4[(k0+1)*256 + tid];
            float w2v = w4[(k0+2)*256 + tid], w3v = w4[(k0+3)*256 + tid];
            #pragma unroll
            for (int r = 0; r < 8; ++r) {
                const float4 a = *(const float4*)&h3[r][k0];
                ac[r] = fmaf(a.x, w0, fmaf(a.y, w1v, fmaf(a.z, w2v, fmaf(a.w, w3v, ac[r]))));
            }
        }
        const float bb = b4[tid];
        #pragma unroll
        for (int r = 0; r < 8; ++r) h4[r][tid] = fmaxf(ac[r] + bb, 0.f);
    }
    __syncthreads();

    // ---- fc5: 256 -> 128
    {
        const int c5 = tid & 127, half = tid >> 7;
        float ac[4];
        #pragma unroll
        for (int r = 0; r < 4; ++r) ac[r] = 0.f;
        for (int kq = 0; kq < 64; ++kq) {
            const int k0 = kq * 4;
            float w0 = w5[(k0+0)*128 + c5], w1v = w5[(k0+1)*128 + c5];
            float w2v = w5[(k0+2)*128 + c5], w3v = w5[(k0+3)*128 + c5];
            #pragma unroll
            for (int r = 0; r < 4; ++r) {
                const float4 a = *(const float4*)&h4[half * 4 + r][k0];
                ac[r] = fmaf(a.x, w0, fmaf(a.y, w1v, fmaf(a.z, w2v, fmaf(a.w, w3v, ac[r]))));
            }
        }
        const float bb = b5[c5];
        #pragma unroll
        for (int r = 0; r < 4; ++r) h5[half * 4 + r][c5] = fmaxf(ac[r] + bb, 0.f);
    }
    __syncthreads();

    // ---- fc6: 128 -> 32
    {
        const int c6 = tid & 31, r = tid >> 5;
        float ac = 0.f;
        for (int kq = 0; kq < 32; ++kq) {
            const int k0 = kq * 4;
            float w0 = w6[(k0+0)*32 + c6], w1v = w6[(k0+1)*32 + c6];
            float w2v = w6[(k0+2)*32 + c6], w3v = w6[(k0+3)*32 + c6];
            const float4 a = *(const float4*)&h5[r][k0];
            ac = fmaf(a.x, w0, fmaf(a.y, w1v, fmaf(a.z, w2v, fmaf(a.w, w3v, ac))));
        }
        z[(size_t)(row0 + r) * 32 + c6] = fmaxf(ac + b6[c6], 0.f);
    }
}

// ------------------------------------------------------------------
// Kernel 3: persistent LSTM (6 layers x 24 steps) + fc10 + top-8
// ------------------------------------------------------------------
__global__ __launch_bounds__(256) void k_lstm(
    const float* __restrict__ z,
    const float* __restrict__ hid0, const float* __restrict__ cel0,
    const float* __restrict__ wih, const float* __restrict__ whh,
    const float* __restrict__ bih, const float* __restrict__ bhh,
    const float* __restrict__ w10, const float* __restrict__ b10,
    int* __restrict__ out)
{
    __shared__ float xs[8][32];
    __shared__ float hs[6][8][32];
    __shared__ float cs[6][8][32];
    __shared__ float gates[8][128];
    __shared__ float logits[8][361];
    const int tid  = threadIdx.x;
    const int row0 = blockIdx.x * 8;

    for (int i = tid; i < 8 * 32; i += 256) xs[0][i] = z[(size_t)row0 * 32 + i];
    for (int i = tid; i < 6 * 8 * 32; i += 256) {
        int l = i >> 8, rj = i & 255;
        (&hs[0][0][0])[i] = hid0[(size_t)l * BATCH * 32 + (size_t)row0 * 32 + rj];
        (&cs[0][0][0])[i] = cel0[(size_t)l * BATCH * 32 + (size_t)row0 * 32 + rj];
    }
    __syncthreads();

    const int g  = tid & 127, rg = tid >> 7;
    const int jc = tid & 31,  jr = tid >> 5;
    const int wv = tid >> 6,  lane = tid & 63;

    for (int t = 0; t < 24; ++t) {
        for (int l = 0; l < 6; ++l) {
            const float* inp = (l == 0) ? ((t == 0) ? &xs[0][0] : &hs[5][0][0])
                                        : &hs[l - 1][0][0];
            const float* WI = wih + (size_t)l * 32 * 128;
            const float* WH = whh + (size_t)l * 32 * 128;
            const float bsum = bih[l * 128 + g] + bhh[l * 128 + g];
            float acc[4] = {bsum, bsum, bsum, bsum};
            #pragma unroll
            for (int k = 0; k < 32; k += 4) {
                float wi0 = WI[(k+0)*128 + g], wi1 = WI[(k+1)*128 + g];
                float wi2 = WI[(k+2)*128 + g], wi3 = WI[(k+3)*128 + g];
                float wh0 = WH[(k+0)*128 + g], wh1 = WH[(k+1)*128 + g];
                float wh2 = WH[(k+2)*128 + g], wh3 = WH[(k+3)*128 + g];
                #pragma unroll
                for (int rr = 0; rr < 4; ++rr) {
                    const int r = rg * 4 + rr;
                    const float4 ai = *(const float4*)&inp[r * 32 + k];
                    const float4 ah = *(const float4*)&hs[l][r][k];
                    acc[rr] = fmaf(ai.x, wi0, acc[rr]); acc[rr] = fmaf(ai.y, wi1, acc[rr]);
                    acc[rr] = fmaf(ai.z, wi2, acc[rr]); acc[rr] = fmaf(ai.w, wi3, acc[rr]);
                    acc[rr] = fmaf(ah.x, wh0, acc[rr]); acc[rr] = fmaf(ah.y, wh1, acc[rr]);
                    acc[rr] = fmaf(ah.z, wh2, acc[rr]); acc[rr] = fmaf(ah.w, wh3, acc[rr]);
                }
            }
            #pragma unroll
            for (int rr = 0; rr < 4; ++rr) gates[rg * 4 + rr][g] = acc[rr];
            __syncthreads();

            {
                const float gi = gates[jr][jc],      gf = gates[jr][32 + jc];
                const float gg = gates[jr][64 + jc], go = gates[jr][96 + jc];
                const float i_ = 1.f / (1.f + expf(-gi));
                const float f_ = 1.f / (1.f + expf(-gf));
                const float o_ = 1.f / (1.f + expf(-go));
                const float g_ = tanhf(gg);
                const float cn = f_ * cs[l][jr][jc] + i_ * g_;
                cs[l][jr][jc] = cn;
                hs[l][jr][jc] = o_ * tanhf(cn);
            }
            __syncthreads();
        }

        // ---- fc10
        #pragma unroll
        for (int pass = 0; pass < 2; ++pass) {
            const int v = tid + pass * 256;
            if (v < 361) {
                const float bb = b10[v];
                float a8[8];
                #pragma unroll
                for (int r = 0; r < 8; ++r) a8[r] = bb;
                #pragma unroll
                for (int k = 0; k < 32; k += 4) {
                    float w0 = w10[(k+0)*361 + v], w1v = w10[(k+1)*361 + v];
                    float w2v = w10[(k+2)*361 + v], w3v = w10[(k+3)*361 + v];
                    #pragma unroll
                    for (int r = 0; r < 8; ++r) {
                        const float4 a = *(const float4*)&hs[5][r][k];
                        a8[r] = fmaf(a.x, w0, fmaf(a.y, w1v, fmaf(a.z, w2v, fmaf(a.w, w3v, a8[r]))));
                    }
                }
                #pragma unroll
                for (int r = 0; r < 8; ++r) logits[r][v] = a8[r];
            }
        }
        __syncthreads();

        // ---- top-8 per row; one wave handles 2 rows.
        for (int rr = 0; rr < 2; ++rr) {
            const int r = wv * 2 + rr;
            float val[6];
            #pragma unroll
            for (int s = 0; s < 6; ++s) {
                const int v = lane + 64 * s;
                val[s] = (v < 361) ? logits[r][v] : -3.4e38f;
            }
            unsigned msk = 0x3Fu;
            const int rowg = row0 + r;
            for (int sel = 0; sel < 8; ++sel) {
                float bv = -3.4e38f; int bi = 0x7FFFFFFF;
                #pragma unroll
                for (int s = 0; s < 6; ++s) {
                    if (msk & (1u << s)) {
                        const float v2 = val[s]; const int i2 = lane + 64 * s;
                        if (v2 > bv || (v2 == bv && i2 < bi)) { bv = v2; bi = i2; }
                    }
                }
                #pragma unroll
                for (int off = 32; off >= 1; off >>= 1) {
                    const float ov = __shfl_xor(bv, off, 64);
                    const int   oi = __shfl_xor(bi, off, 64);
                    if (ov > bv || (ov == bv && oi < bi)) { bv = ov; bi = oi; }
                }
                if ((bi & 63) == lane) msk &= ~(1u << (bi >> 6));
                if (lane == 0) out[(size_t)rowg * 192 + t * 8 + sel] = bi;
            }
        }
        __syncthreads();
    }
}

// ------------------------------------------------------------------
extern "C" void kernel_launch(void* const* d_in, const int* in_sizes, int n_in,
                              void* d_out, int out_size, void* d_ws, size_t ws_size,
                              hipStream_t stream) {
    const float* cin  = (const float*)d_in[0];
    const float* x    = (const float*)d_in[1];
    const float* hid0 = (const float*)d_in[2];
    const float* cel0 = (const float*)d_in[3];
    const float* w1 = (const float*)d_in[4];  const float* b1 = (const float*)d_in[5];
    const float* w2 = (const float*)d_in[6];  const float* b2 = (const float*)d_in[7];
    const float* w3 = (const float*)d_in[8];  const float* b3 = (const float*)d_in[9];
    const float* w4 = (const float*)d_in[10]; const float* b4 = (const float*)d_in[11];
    const float* w5 = (const float*)d_in[12]; const float* b5 = (const float*)d_in[13];
    const float* w6 = (const float*)d_in[14]; const float* b6 = (const float*)d_in[15];
    const float* wih = (const float*)d_in[16]; const float* whh = (const float*)d_in[17];
    const float* bih = (const float*)d_in[18]; const float* bhh = (const float*)d_in[19];
    const float* w10 = (const float*)d_in[20]; const float* b10 = (const float*)d_in[21];

    float* xp = (float*)d_ws;                       // 4096 x 256
    float* zz = xp + (size_t)BATCH * 256;           // 4096 x 32
    int*   out = (int*)d_out;

    k_encoder<<<BATCH, 256, 0, stream>>>(x, w1, b1, w2, b2, xp);
    k_mlp<<<BATCH / 8, 256, 0, stream>>>(cin, xp, w3, b3, w4, b4, w5, b5, w6, b6, zz);
    k_lstm<<<BATCH / 8, 256, 0, stream>>>(zz, hid0, cel0, wih, whh, bih, bhh, w10, b10, out);
}